// Round 3
// baseline (560.171 us; speedup 1.0000x reference)
//
#include <hip/hip_runtime.h>
#include <math.h>

#define GW 38
#define GH 38
#define NA 25
#define NB 512
#define HW (GW * GH)              // 1444 cells per plane
#define PLANE_F (5 * HW)          // 7220 floats per (b,a) plane-group
#define PLANE_V (PLANE_F / 4)     // 1805 float4
#define NBLOCKS (NB * NA)         // 12800 blocks, one per (b,a)
#define BLK 256

struct Meta {
    float gxlo, gxhi, gylo, gyhi;  // gx -/+ gw/2, gy -/+ gh/2
    float gw, gh, area;            // gw*gh
    float tconf, tb0, tb1, tb2, tb3;
    int   best, cell;              // cell = gj*38 + gi
};

__device__ __forceinline__ float fast_rcp(float x) { return __builtin_amdgcn_rcpf(x); }
__device__ __forceinline__ float fast_exp(float x) { return __expf(x); }   // v_exp_f32
__device__ __forceinline__ float fast_sig(float x) { return fast_rcp(1.0f + fast_exp(-x)); }

__device__ __forceinline__ float iou_precise(float x1, float y1, float w1, float h1,
                                             float x2, float y2, float w2, float h2) {
    float mx = fminf(x1 - w1 * 0.5f, x2 - w2 * 0.5f);
    float Mx = fmaxf(x1 + w1 * 0.5f, x2 + w2 * 0.5f);
    float my = fminf(y1 - h1 * 0.5f, y2 - h2 * 0.5f);
    float My = fmaxf(y1 + h1 * 0.5f, y2 + h2 * 0.5f);
    float cw = w1 + w2 - (Mx - mx);
    float ch = h1 + h2 - (My - my);
    float inter = (cw > 0.0f && ch > 0.0f) ? cw * ch : 0.0f;
    float uni = w1 * h1 + w2 * h2 - inter;
    return inter / uni;
}

// anchors = float32(_BASE) * float32(scale), scale in {0.5,0.75,1.0,1.25,1.5}
__device__ __forceinline__ void anchor_wh(int a, float* aw, float* ah) {
    const float bw[5] = {1.3221f, 3.19275f, 5.05587f, 9.47112f, 11.2364f};
    const float bh[5] = {1.73145f, 4.00944f, 8.09892f, 4.84053f, 10.0071f};
    float s = 0.5f + 0.25f * (float)(a / 5);
    *aw = bw[a % 5] * s;
    *ah = bh[a % 5] * s;
}

__global__ void meta_kernel(const float* __restrict__ pred,
                            const float* __restrict__ target,
                            Meta* __restrict__ metas) {
    int b = blockIdx.x * blockDim.x + threadIdx.x;
    if (b >= NB) return;
    float gx = target[b * 4 + 0] * (float)GW;
    float gy = target[b * 4 + 1] * (float)GH;
    float gw = target[b * 4 + 2] * (float)GW;
    float gh = target[b * 4 + 3] * (float)GH;
    int best = 0;
    float best_iou = -1.0f;
    for (int a = 0; a < NA; ++a) {
        float aw, ah;
        anchor_wh(a, &aw, &ah);
        float v = iou_precise(0.0f, 0.0f, aw, ah, 0.0f, 0.0f, gw, gh);
        if (v > best_iou) { best_iou = v; best = a; }
    }
    int gi = (int)gx;
    int gj = (int)gy;
    float aw, ah;
    anchor_wh(best, &aw, &ah);
    size_t base = (size_t)b * NA * 5 * HW + (size_t)(best * 5) * HW + gj * GW + gi;
    float p0 = pred[base + 0 * HW];
    float p1 = pred[base + 1 * HW];
    float p2 = pred[base + 2 * HW];
    float p3 = pred[base + 3 * HW];
    float pbx = 1.0f / (1.0f + expf(-p0)) + (float)gi;   // precise path (512 cells only)
    float pby = 1.0f / (1.0f + expf(-p1)) + (float)gj;
    float pbw = expf(p2) * aw;
    float pbh = expf(p3) * ah;
    Meta m;
    m.gxlo = gx - gw * 0.5f; m.gxhi = gx + gw * 0.5f;
    m.gylo = gy - gh * 0.5f; m.gyhi = gy + gh * 0.5f;
    m.gw = gw; m.gh = gh; m.area = gw * gh;
    m.tconf = iou_precise(pbx, pby, pbw, pbh, gx, gy, gw, gh);
    m.tb0 = gx - (float)gi;
    m.tb1 = gy - (float)gj;
    m.tb2 = logf(gw / aw);
    m.tb3 = logf(gh / ah);
    m.best = best;
    m.cell = gj * GW + gi;
    metas[b] = m;
}

// per-cell loss: coords (dx²+dy²+dw²+dh²) + masked conf term
__device__ __forceinline__ float cell_loss(float p0, float p1, float p2, float p3, float p4,
                                           float fi, float fj, bool obj,
                                           const Meta& m, float aw, float ah) {
    float tx = fast_sig(p0);
    float ty = fast_sig(p1);
    float conf = fast_sig(p4);
    float bw = fast_exp(p2) * aw;
    float bh = fast_exp(p3) * ah;
    float bx = tx + fi;
    float by = ty + fj;
    float mx = fminf(bx - bw * 0.5f, m.gxlo);
    float Mx = fmaxf(bx + bw * 0.5f, m.gxhi);
    float my = fminf(by - bh * 0.5f, m.gylo);
    float My = fmaxf(by + bh * 0.5f, m.gyhi);
    float cw = bw + m.gw - (Mx - mx);
    float ch = bh + m.gh - (My - my);
    float inter = (cw > 0.0f && ch > 0.0f) ? cw * ch : 0.0f;
    float uni = bw * bh + m.area - inter;
    float iou = inter * fast_rcp(uni);
    float cm = obj ? 2.23606797749979f : ((iou > 0.6f) ? 0.0f : 1.0f);  // sqrt(5)/0/1
    float dx = tx - (obj ? m.tb0 : 0.5f);
    float dy = ty - (obj ? m.tb1 : 0.5f);
    float dw = p2 - (obj ? m.tb2 : 0.0f);
    float dh = p3 - (obj ? m.tb3 : 0.0f);
    float dc = cm * (conf - (obj ? m.tconf : 0.0f));
    return dx * dx + dy * dy + dw * dw + dh * dh + dc * dc;
}

// One block per (b,a) plane-group. Phase 1: stream the contiguous 28.9 KB
// chunk into LDS with float4 loads (same global pattern as a memcpy —
// long sequential runs per block). Phase 2: gather the 5 channels per cell
// from LDS (stride HW floats; consecutive lanes → consecutive banks, the
// wave64 2-way aliasing is free).
__global__ __launch_bounds__(BLK) void loss_kernel(const float* __restrict__ pred,
                                                   const Meta* __restrict__ metas,
                                                   float* __restrict__ out) {
    __shared__ float4 lds4[PLANE_V];
    float* lds = (float*)lds4;

    unsigned plane = blockIdx.x;           // b*25 + a  (wave-uniform)
    unsigned b = plane / (unsigned)NA;
    unsigned a = plane - b * (unsigned)NA;

    const float4* src = (const float4*)(pred + (size_t)plane * (unsigned)PLANE_F);
#pragma unroll
    for (int r = 0; r < 8; ++r) {
        unsigned idx = threadIdx.x + (unsigned)(r * BLK);
        if (idx < (unsigned)PLANE_V) lds4[idx] = src[idx];
    }

    // scalar-path meta (b is wave-uniform)
    Meta m = metas[b];
    float aw, ah;
    anchor_wh((int)a, &aw, &ah);
    bool aok = (a == (unsigned)m.best);

    __syncthreads();

    float acc = 0.0f;
#pragma unroll
    for (int r = 0; r < 6; ++r) {
        unsigned s = threadIdx.x + (unsigned)(r * BLK);
        if (s < (unsigned)HW) {
            float p0 = lds[0 * HW + s];
            float p1 = lds[1 * HW + s];
            float p2 = lds[2 * HW + s];
            float p3 = lds[3 * HW + s];
            float p4 = lds[4 * HW + s];
            unsigned j = s / (unsigned)GW;
            unsigned i = s - j * (unsigned)GW;
            bool obj = aok && (s == (unsigned)m.cell);
            acc += cell_loss(p0, p1, p2, p3, p4, (float)i, (float)j, obj, m, aw, ah);
        }
    }

    // wave64 shuffle reduce → LDS across 4 waves → one atomic per block
    for (int off = 32; off > 0; off >>= 1)
        acc += __shfl_down(acc, off, 64);
    __shared__ float sm[BLK / 64];
    int lane = (int)(threadIdx.x & 63u);
    int wv = (int)(threadIdx.x >> 6u);
    if (lane == 0) sm[wv] = acc;
    __syncthreads();
    if (threadIdx.x == 0) {
        float s = sm[0] + sm[1] + sm[2] + sm[3];
        atomicAdd(out, 0.5f * s);
    }
}

extern "C" void kernel_launch(void* const* d_in, const int* in_sizes, int n_in,
                              void* d_out, int out_size, void* d_ws, size_t ws_size,
                              hipStream_t stream) {
    const float* pred = (const float*)d_in[0];
    const float* target = (const float*)d_in[1];
    float* out = (float*)d_out;
    Meta* metas = (Meta*)d_ws;

    hipMemsetAsync(d_out, 0, (size_t)out_size * sizeof(float), stream);
    meta_kernel<<<(NB + BLK - 1) / BLK, BLK, 0, stream>>>(pred, target, metas);
    loss_kernel<<<NBLOCKS, BLK, 0, stream>>>(pred, metas, out);
}